// Round 1
// baseline (2589.583 us; speedup 1.0000x reference)
//
#include <hip/hip_runtime.h>
#include <hip/hip_bf16.h>
#include <math.h>

#define BATCH 16384
#define EMB_DIM 128
#define NUM_CAT 26
#define TABLE_SIZE 100000
#define NUM_FEATS 27
#define NUM_PAIRS 351        // 27*26/2
#define TOP_IN 480           // 128 + 351 + 1

// ---------------------------------------------------------------------------
// Layer 1 of bottom MLP: out[B,512] = relu(num[B,13] @ w[512,13]^T + b)
// K=13 is too small to tile; one thread per output element.
// ---------------------------------------------------------------------------
__global__ __launch_bounds__(256) void bottom_l1(
    const float* __restrict__ num, const float* __restrict__ w,
    const float* __restrict__ bias, float* __restrict__ out)
{
    int idx = blockIdx.x * 256 + threadIdx.x;       // [0, 16384*512)
    int b = idx >> 9;
    int n = idx & 511;
    float acc = bias[n];
    const float* nr = num + (size_t)b * 13;
    const float* wr = w + (size_t)n * 13;
#pragma unroll
    for (int k = 0; k < 13; ++k) acc = fmaf(nr[k], wr[k], acc);
    out[idx] = fmaxf(acc, 0.f);
}

// ---------------------------------------------------------------------------
// Tiled fp32 GEMM:  C[M,N] = relu(A[M,K] @ W[N,K]^T + bias[N])
// Requires M%64==0, N%64==0, K%16==0.  64x64 tile, 256 threads, 4x4/thread.
// ---------------------------------------------------------------------------
__global__ __launch_bounds__(256) void gemm_nt_relu(
    const float* __restrict__ A, const float* __restrict__ W,
    const float* __restrict__ bias, float* __restrict__ C,
    int M, int N, int K)
{
    __shared__ __align__(16) float As[16][68];   // [k][m], stride 68 floats = 272B (16B aligned)
    __shared__ __align__(16) float Ws[16][68];   // [k][n]

    const int tid = threadIdx.x;
    const int bm = blockIdx.y * 64;
    const int bn = blockIdx.x * 64;

    const int tx = tid & 15;        // n-quad
    const int ty = tid >> 4;        // m-quad

    const int lrow = tid >> 2;            // 0..63
    const int lk4  = (tid & 3) * 4;       // 0,4,8,12

    const float* Ap = A + (size_t)(bm + lrow) * K + lk4;
    const float* Wp = W + (size_t)(bn + lrow) * K + lk4;

    float acc[4][4] = {};

    for (int k0 = 0; k0 < K; k0 += 16) {
        const float4 av = *(const float4*)(Ap + k0);
        const float4 wv = *(const float4*)(Wp + k0);
        __syncthreads();
        As[lk4 + 0][lrow] = av.x; As[lk4 + 1][lrow] = av.y;
        As[lk4 + 2][lrow] = av.z; As[lk4 + 3][lrow] = av.w;
        Ws[lk4 + 0][lrow] = wv.x; Ws[lk4 + 1][lrow] = wv.y;
        Ws[lk4 + 2][lrow] = wv.z; Ws[lk4 + 3][lrow] = wv.w;
        __syncthreads();
#pragma unroll
        for (int kk = 0; kk < 16; ++kk) {
            const float4 a = *(const float4*)&As[kk][ty * 4];
            const float4 w = *(const float4*)&Ws[kk][tx * 4];
            acc[0][0] = fmaf(a.x, w.x, acc[0][0]);
            acc[0][1] = fmaf(a.x, w.y, acc[0][1]);
            acc[0][2] = fmaf(a.x, w.z, acc[0][2]);
            acc[0][3] = fmaf(a.x, w.w, acc[0][3]);
            acc[1][0] = fmaf(a.y, w.x, acc[1][0]);
            acc[1][1] = fmaf(a.y, w.y, acc[1][1]);
            acc[1][2] = fmaf(a.y, w.z, acc[1][2]);
            acc[1][3] = fmaf(a.y, w.w, acc[1][3]);
            acc[2][0] = fmaf(a.z, w.x, acc[2][0]);
            acc[2][1] = fmaf(a.z, w.y, acc[2][1]);
            acc[2][2] = fmaf(a.z, w.z, acc[2][2]);
            acc[2][3] = fmaf(a.z, w.w, acc[2][3]);
            acc[3][0] = fmaf(a.w, w.x, acc[3][0]);
            acc[3][1] = fmaf(a.w, w.y, acc[3][1]);
            acc[3][2] = fmaf(a.w, w.z, acc[3][2]);
            acc[3][3] = fmaf(a.w, w.w, acc[3][3]);
        }
    }

    const float4 bv = *(const float4*)(bias + bn + tx * 4);
#pragma unroll
    for (int i = 0; i < 4; ++i) {
        float4 r;
        r.x = fmaxf(acc[i][0] + bv.x, 0.f);
        r.y = fmaxf(acc[i][1] + bv.y, 0.f);
        r.z = fmaxf(acc[i][2] + bv.z, 0.f);
        r.w = fmaxf(acc[i][3] + bv.w, 0.f);
        *(float4*)(C + (size_t)(bm + ty * 4 + i) * N + bn + tx * 4) = r;
    }
}

// ---------------------------------------------------------------------------
// Embedding gather + pairwise interaction.  One block per sample.
// x[b, 0:128]   = bottom[b]
// x[b, 128+p]   = feats[r_p] . feats[c_p]   (np.tril_indices(27,-1) order)
// x[b, 479]     = 0
// ---------------------------------------------------------------------------
__global__ __launch_bounds__(256) void interact(
    const float* __restrict__ bottom, const int* __restrict__ cat,
    const float* __restrict__ tables, float* __restrict__ x)
{
    __shared__ float feats[NUM_FEATS][EMB_DIM + 4];   // pad → spread banks in dot loop

    const int b = blockIdx.x;
    const int tid = threadIdx.x;

    for (int i = tid; i < NUM_FEATS * EMB_DIM; i += 256) {
        const int f = i >> 7;
        const int k = i & 127;
        float v;
        if (f == 0) {
            v = bottom[(size_t)b * EMB_DIM + k];
        } else {
            const int row = cat[(size_t)(f - 1) * BATCH + b];
            v = tables[((size_t)(f - 1) * TABLE_SIZE + row) * EMB_DIM + k];
        }
        feats[f][k] = v;
    }
    __syncthreads();

    float* xr = x + (size_t)b * TOP_IN;
    if (tid < 128) xr[tid] = feats[0][tid];
    if (tid == 255) xr[479] = 0.f;

    for (int p = tid; p < NUM_PAIRS; p += 256) {
        int r = (int)((1.0f + sqrtf(1.0f + 8.0f * (float)p)) * 0.5f);
        if (r * (r - 1) / 2 > p) --r;
        if ((r + 1) * r / 2 <= p) ++r;
        const int c = p - r * (r - 1) / 2;
        float acc = 0.f;
#pragma unroll 16
        for (int k = 0; k < EMB_DIM; ++k)
            acc = fmaf(feats[r][k], feats[c][k], acc);
        xr[128 + p] = acc;
    }
}

// ---------------------------------------------------------------------------
// Final layer: out[b] = sigmoid(t4[b,:256] . w + bias).  One wave per row.
// ---------------------------------------------------------------------------
__global__ __launch_bounds__(256) void top_final(
    const float* __restrict__ A, const float* __restrict__ w,
    const float* __restrict__ bias, float* __restrict__ out)
{
    const int wave = threadIdx.x >> 6;
    const int lane = threadIdx.x & 63;
    const int b = blockIdx.x * 4 + wave;
    const float* row = A + (size_t)b * 256;
    float acc = 0.f;
#pragma unroll
    for (int k = lane; k < 256; k += 64) acc = fmaf(row[k], w[k], acc);
#pragma unroll
    for (int off = 32; off > 0; off >>= 1) acc += __shfl_down(acc, off, 64);
    if (lane == 0) out[b] = 1.f / (1.f + expf(-(acc + bias[0])));
}

// ---------------------------------------------------------------------------
extern "C" void kernel_launch(void* const* d_in, const int* in_sizes, int n_in,
                              void* d_out, int out_size, void* d_ws, size_t ws_size,
                              hipStream_t stream)
{
    const float* num    = (const float*)d_in[0];
    const int*   cat    = (const int*)  d_in[1];
    const float* tables = (const float*)d_in[2];
    const float* bw1 = (const float*)d_in[3];  const float* bb1 = (const float*)d_in[4];
    const float* bw2 = (const float*)d_in[5];  const float* bb2 = (const float*)d_in[6];
    const float* bw3 = (const float*)d_in[7];  const float* bb3 = (const float*)d_in[8];
    const float* tw1 = (const float*)d_in[9];  const float* tb1 = (const float*)d_in[10];
    const float* tw2 = (const float*)d_in[11]; const float* tb2 = (const float*)d_in[12];
    const float* tw3 = (const float*)d_in[13]; const float* tb3 = (const float*)d_in[14];
    const float* tw4 = (const float*)d_in[15]; const float* tb4 = (const float*)d_in[16];
    const float* tw5 = (const float*)d_in[17]; const float* tb5 = (const float*)d_in[18];
    float* out = (float*)d_out;

    // Workspace: two 64MB ping-pong buffers.  bottom (8MB) lives in the dead
    // tail of bufB (h2 only occupies the first 16MB of bufB at that point).
    float* bufA   = (float*)d_ws;                       // 16384*1024 floats
    float* bufB   = bufA + (size_t)BATCH * 1024;        // 16384*1024 floats
    float* botbuf = bufB + (size_t)BATCH * 256;         // 16384*128 floats (tail of bufB)

    // Bottom MLP
    bottom_l1<<<BATCH * 512 / 256, 256, 0, stream>>>(num, bw1, bb1, bufA);
    gemm_nt_relu<<<dim3(256 / 64, BATCH / 64), 256, 0, stream>>>(bufA, bw2, bb2, bufB, BATCH, 256, 512);
    gemm_nt_relu<<<dim3(128 / 64, BATCH / 64), 256, 0, stream>>>(bufB, bw3, bb3, botbuf, BATCH, 128, 256);

    // Embedding gather + interactions → x[B,480] in bufA
    interact<<<BATCH, 256, 0, stream>>>(botbuf, cat, tables, bufA);

    // Top MLP
    gemm_nt_relu<<<dim3(1024 / 64, BATCH / 64), 256, 0, stream>>>(bufA, tw1, tb1, bufB, BATCH, 1024, 480);
    gemm_nt_relu<<<dim3(1024 / 64, BATCH / 64), 256, 0, stream>>>(bufB, tw2, tb2, bufA, BATCH, 1024, 1024);
    gemm_nt_relu<<<dim3(512 / 64, BATCH / 64), 256, 0, stream>>>(bufA, tw3, tb3, bufB, BATCH, 512, 1024);
    gemm_nt_relu<<<dim3(256 / 64, BATCH / 64), 256, 0, stream>>>(bufB, tw4, tb4, bufA, BATCH, 256, 512);
    top_final<<<BATCH / 4, 256, 0, stream>>>(bufA, tw5, tb5, out);
}

// Round 2
// 1688.975 us; speedup vs baseline: 1.5332x; 1.5332x over previous
//
#include <hip/hip_runtime.h>
#include <math.h>

#define BATCH 16384
#define EMB_DIM 128
#define TABLE_SIZE 100000

typedef __attribute__((ext_vector_type(8))) short short8;
typedef __attribute__((ext_vector_type(4))) float floatx4;
typedef __attribute__((ext_vector_type(4))) unsigned short ushort4v;

typedef __attribute__((address_space(3))) unsigned lds_u;
typedef const __attribute__((address_space(1))) unsigned glob_u;

__device__ __forceinline__ void async_copy16(const void* g, void* l) {
    __builtin_amdgcn_global_load_lds((glob_u*)g, (lds_u*)l, 16, 0, 0);
}

__device__ __forceinline__ unsigned short f2bf(float f) {
    unsigned u = __builtin_bit_cast(unsigned, f);
    u += 0x7fff + ((u >> 16) & 1);          // RNE; inputs finite
    return (unsigned short)(u >> 16);
}
__device__ __forceinline__ float bf2f(unsigned short h) {
    unsigned u = ((unsigned)h) << 16;
    return __builtin_bit_cast(float, u);
}

// ---------------------------------------------------------------------------
// Convert 6 fp32 weight matrices to bf16 (contiguous region starting at dst).
// Region boundaries in elements (all multiples of 4).
// ---------------------------------------------------------------------------
#define CW0 131072            // bw2 256x512
#define CW1 (CW0 + 32768)     // bw3 128x256
#define CW2 (CW1 + 491520)    // tw1 1024x480
#define CW3 (CW2 + 1048576)   // tw2 1024x1024
#define CW4 (CW3 + 524288)    // tw3 512x1024
#define CW5 (CW4 + 131072)    // tw4 256x512
__global__ __launch_bounds__(256) void cvt6(
    const float* __restrict__ a, const float* __restrict__ b,
    const float* __restrict__ c, const float* __restrict__ d,
    const float* __restrict__ e, const float* __restrict__ f,
    unsigned short* __restrict__ dst)
{
    int base = (blockIdx.x * 256 + threadIdx.x) * 4;
    if (base >= CW5) return;
    const float* s; int local;
    if      (base < CW0) { s = a; local = base; }
    else if (base < CW1) { s = b; local = base - CW0; }
    else if (base < CW2) { s = c; local = base - CW1; }
    else if (base < CW3) { s = d; local = base - CW2; }
    else if (base < CW4) { s = e; local = base - CW3; }
    else                 { s = f; local = base - CW4; }
    float4 v = *(const float4*)(s + local);
    ushort4v o;
    o.x = f2bf(v.x); o.y = f2bf(v.y); o.z = f2bf(v.z); o.w = f2bf(v.w);
    *(ushort4v*)(dst + base) = o;
}

// ---------------------------------------------------------------------------
// Bottom layer 1: out[B,512] = relu(num[B,13] @ w[512,13]^T + b), bf16 out.
// Each thread computes 2 adjacent n (4B packed store).
// ---------------------------------------------------------------------------
__global__ __launch_bounds__(256) void bottom_l1(
    const float* __restrict__ num, const float* __restrict__ w,
    const float* __restrict__ bias, unsigned short* __restrict__ out)
{
    int idx = blockIdx.x * 256 + threadIdx.x;   // B*256
    int b = idx >> 8;
    int n0 = (idx & 255) * 2;
    const float* nr = num + (size_t)b * 13;
    const float* w0 = w + (size_t)n0 * 13;
    float a0 = bias[n0], a1 = bias[n0 + 1];
#pragma unroll
    for (int k = 0; k < 13; ++k) {
        float nv = nr[k];
        a0 = fmaf(nv, w0[k], a0);
        a1 = fmaf(nv, w0[13 + k], a1);
    }
    unsigned p = (unsigned)f2bf(fmaxf(a0, 0.f)) | ((unsigned)f2bf(fmaxf(a1, 0.f)) << 16);
    *(unsigned*)(out + (size_t)b * 512 + n0) = p;
}

// ---------------------------------------------------------------------------
// bf16 MFMA GEMM: C[M,N] = relu(A[M,K] @ W[N,K]^T + bias), bf16 in/out,
// fp32 accumulate.  128x128 tile, BK=32, 256 threads (4 waves, 2x2),
// global_load_lds width-16 staging (m97 structure).
// Requires M%128==0, N%128==0, K%32==0.
// ---------------------------------------------------------------------------
__global__ __launch_bounds__(256) void gemm_bf16(
    const unsigned short* __restrict__ A,   // [M,K]
    const unsigned short* __restrict__ W,   // [N,K]
    const float* __restrict__ bias,
    unsigned short* __restrict__ C,         // [M,N]
    int M, int N, int K)
{
    __shared__ unsigned short As[128 * 32];
    __shared__ unsigned short Bs[128 * 32];

    const int tid = threadIdx.x;
    const int wave = tid >> 6, lane = tid & 63;
    const int wm = (wave >> 1) * 64, wn = (wave & 1) * 64;
    const int bm = blockIdx.y * 128, bn = blockIdx.x * 128;

    // Staging: wave covers rows [wave*32, wave*32+32) in two 16-row chunks.
    const int srow = wave * 32 + (lane >> 2);
    const int skof = (lane & 3) * 8;                  // bf16 elements
    const unsigned short* Ag0 = A + (size_t)(bm + srow) * K + skof;
    const unsigned short* Ag1 = Ag0 + (size_t)16 * K;
    const unsigned short* Wg0 = W + (size_t)(bn + srow) * K + skof;
    const unsigned short* Wg1 = Wg0 + (size_t)16 * K;
    unsigned short* Al0 = As + (wave * 32) * 32;
    unsigned short* Al1 = Al0 + 16 * 32;
    unsigned short* Bl0 = Bs + (wave * 32) * 32;
    unsigned short* Bl1 = Bl0 + 16 * 32;

    const int mrow = lane & 15;
    const int kq   = (lane >> 4) * 8;

    floatx4 acc[4][4];
#pragma unroll
    for (int i = 0; i < 4; ++i)
#pragma unroll
        for (int j = 0; j < 4; ++j)
            acc[i][j] = (floatx4){0.f, 0.f, 0.f, 0.f};

    for (int k0 = 0; k0 < K; k0 += 32) {
        __syncthreads();                       // prior ds_reads done
        async_copy16(Ag0, Al0);
        async_copy16(Ag1, Al1);
        async_copy16(Wg0, Bl0);
        async_copy16(Wg1, Bl1);
        Ag0 += 32; Ag1 += 32; Wg0 += 32; Wg1 += 32;
        __syncthreads();                       // vmcnt drained before reads

        short8 af[4], wf[4];
#pragma unroll
        for (int i = 0; i < 4; ++i)
            af[i] = *(const short8*)&As[(wm + i * 16 + mrow) * 32 + kq];
#pragma unroll
        for (int j = 0; j < 4; ++j)
            wf[j] = *(const short8*)&Bs[(wn + j * 16 + mrow) * 32 + kq];
#pragma unroll
        for (int i = 0; i < 4; ++i)
#pragma unroll
            for (int j = 0; j < 4; ++j)
                acc[i][j] = __builtin_amdgcn_mfma_f32_16x16x32_bf16(af[i], wf[j], acc[i][j], 0, 0, 0);
    }

    // Epilogue: C/D layout col=lane&15, row=(lane>>4)*4+reg.
#pragma unroll
    for (int j = 0; j < 4; ++j) {
        const int col = bn + wn + j * 16 + (lane & 15);
        const float bv = bias[col];
#pragma unroll
        for (int i = 0; i < 4; ++i) {
            const int rbase = bm + wm + i * 16 + (lane >> 4) * 4;
#pragma unroll
            for (int r = 0; r < 4; ++r) {
                float v = acc[i][j][r] + bv;
                C[(size_t)(rbase + r) * N + col] = f2bf(fmaxf(v, 0.f));
            }
        }
    }
}

// ---------------------------------------------------------------------------
// Embedding gather + pairwise interaction via per-sample 32x32 Gram (MFMA).
// One wave per sample, 4 samples per block.
// x[b,0:128]=bottom(bf16), x[b,128+tri(r,c)]=feat_r.feat_c, x[b,479]=0.
// ---------------------------------------------------------------------------
__global__ __launch_bounds__(256) void interact_mfma(
    const unsigned short* __restrict__ bot,   // [B,128] bf16
    const int* __restrict__ cat,              // [26,B]
    const float* __restrict__ tables,         // [26,100000,128] f32
    unsigned short* __restrict__ x)           // [B,480] bf16
{
    __shared__ unsigned short F[4][32][136];  // pad 136: 2-way (free) on frag reads

    const int wave = threadIdx.x >> 6, lane = threadIdx.x & 63;
    const int b = blockIdx.x * 4 + wave;
    unsigned short (*Fw)[136] = F[wave];
    unsigned short* xr = x + (size_t)b * 480;

    // indices: lane l<26 holds cat[l][b]
    int idx0 = (lane < 26) ? cat[(size_t)lane * BATCH + b] : 0;

    // row 0 = bottom (bf16 copy, also to x[0:128])
    {
        unsigned v = *(const unsigned*)(bot + (size_t)b * 128 + lane * 2);
        *(unsigned*)&Fw[0][lane * 2] = v;
        *(unsigned*)(xr + lane * 2) = v;
    }
    if (lane == 63) xr[479] = 0;

    // rows 1..26 = embedding rows (fp32 -> bf16)
    for (int f = 1; f <= 26; ++f) {
        int row = __shfl(idx0, f - 1, 64);
        float2 v = *(const float2*)(tables + ((size_t)(f - 1) * TABLE_SIZE + row) * EMB_DIM + lane * 2);
        unsigned p = (unsigned)f2bf(v.x) | ((unsigned)f2bf(v.y) << 16);
        *(unsigned*)&Fw[f][lane * 2] = p;
    }
    // rows 27..31 = 0 (pad)
#pragma unroll
    for (int f = 27; f < 32; ++f) *(unsigned*)&Fw[f][lane * 2] = 0;

    __syncthreads();   // cheap safety: cross-lane LDS visibility + sched fence

    // frags: rowblock i (0,1), kq q (0..3); same data serves A and B operands
    short8 fr[2][4];
#pragma unroll
    for (int i = 0; i < 2; ++i)
#pragma unroll
        for (int q = 0; q < 4; ++q)
            fr[i][q] = *(const short8*)&Fw[i * 16 + (lane & 15)][q * 8];

    floatx4 c00 = {0.f, 0.f, 0.f, 0.f}, c10 = c00, c11 = c00;
#pragma unroll
    for (int q = 0; q < 4; ++q) {
        c00 = __builtin_amdgcn_mfma_f32_16x16x32_bf16(fr[0][q], fr[0][q], c00, 0, 0, 0);
        c10 = __builtin_amdgcn_mfma_f32_16x16x32_bf16(fr[1][q], fr[0][q], c10, 0, 0, 0);
        c11 = __builtin_amdgcn_mfma_f32_16x16x32_bf16(fr[1][q], fr[1][q], c11, 0, 0, 0);
    }

    // store lower triangle: tri(r,c) = r(r-1)/2 + c
    const int cl = lane & 15, rl = (lane >> 4) * 4;
#pragma unroll
    for (int r = 0; r < 4; ++r) {
        int rr = rl + r, cc = cl;
        if (rr > cc)                    xr[128 + (rr * (rr - 1)) / 2 + cc] = f2bf(c00[r]);
    }
#pragma unroll
    for (int r = 0; r < 4; ++r) {
        int rr = 16 + rl + r, cc = cl;
        if (rr < 27)                    xr[128 + (rr * (rr - 1)) / 2 + cc] = f2bf(c10[r]);
    }
#pragma unroll
    for (int r = 0; r < 4; ++r) {
        int rr = 16 + rl + r, cc = 16 + cl;
        if (rr < 27 && rr > cc)         xr[128 + (rr * (rr - 1)) / 2 + cc] = f2bf(c11[r]);
    }
}

// ---------------------------------------------------------------------------
// Final layer: out[b] = sigmoid(h4[b,:256] . w + bias). One wave per row.
// ---------------------------------------------------------------------------
__global__ __launch_bounds__(256) void top_final(
    const unsigned short* __restrict__ A, const float* __restrict__ w,
    const float* __restrict__ bias, float* __restrict__ out)
{
    const int wave = threadIdx.x >> 6, lane = threadIdx.x & 63;
    const int b = blockIdx.x * 4 + wave;
    const unsigned short* row = A + (size_t)b * 256;
    float acc = 0.f;
#pragma unroll
    for (int k = lane; k < 256; k += 64) acc = fmaf(bf2f(row[k]), w[k], acc);
#pragma unroll
    for (int off = 32; off > 0; off >>= 1) acc += __shfl_down(acc, off, 64);
    if (lane == 0) out[b] = 1.f / (1.f + expf(-(acc + bias[0])));
}

// ---------------------------------------------------------------------------
extern "C" void kernel_launch(void* const* d_in, const int* in_sizes, int n_in,
                              void* d_out, int out_size, void* d_ws, size_t ws_size,
                              hipStream_t stream)
{
    const float* num    = (const float*)d_in[0];
    const int*   cat    = (const int*)  d_in[1];
    const float* tables = (const float*)d_in[2];
    const float* bw1 = (const float*)d_in[3];  const float* bb1 = (const float*)d_in[4];
    const float* bw2 = (const float*)d_in[5];  const float* bb2 = (const float*)d_in[6];
    const float* bw3 = (const float*)d_in[7];  const float* bb3 = (const float*)d_in[8];
    const float* tw1 = (const float*)d_in[9];  const float* tb1 = (const float*)d_in[10];
    const float* tw2 = (const float*)d_in[11]; const float* tb2 = (const float*)d_in[12];
    const float* tw3 = (const float*)d_in[13]; const float* tb3 = (const float*)d_in[14];
    const float* tw4 = (const float*)d_in[15]; const float* tb4 = (const float*)d_in[16];
    const float* tw5 = (const float*)d_in[17]; const float* tb5 = (const float*)d_in[18];
    float* out = (float*)d_out;

    // workspace carve-up (bf16 buffers)
    char* p = (char*)d_ws;
    unsigned short* wbf  = (unsigned short*)p; p += (size_t)CW5 * 2;        // all 6 weights
    unsigned short* act1 = (unsigned short*)p; p += (size_t)BATCH * 512 * 2;
    unsigned short* act2 = (unsigned short*)p; p += (size_t)BATCH * 256 * 2;
    unsigned short* bot  = (unsigned short*)p; p += (size_t)BATCH * 128 * 2;
    unsigned short* xbuf = (unsigned short*)p; p += (size_t)BATCH * 480 * 2;
    unsigned short* h1   = (unsigned short*)p; p += (size_t)BATCH * 1024 * 2;
    unsigned short* h2   = (unsigned short*)p; p += (size_t)BATCH * 1024 * 2;
    unsigned short* h3   = (unsigned short*)p; p += (size_t)BATCH * 512 * 2;
    unsigned short* h4   = (unsigned short*)p;

    unsigned short* wb2 = wbf;
    unsigned short* wb3 = wbf + CW0;
    unsigned short* wt1 = wbf + CW1;
    unsigned short* wt2 = wbf + CW2;
    unsigned short* wt3 = wbf + CW3;
    unsigned short* wt4 = wbf + CW4;

    cvt6<<<(CW5 / 4 + 255) / 256, 256, 0, stream>>>(bw2, bw3, tw1, tw2, tw3, tw4, wbf);
    bottom_l1<<<BATCH, 256, 0, stream>>>(num, bw1, bb1, act1);

    gemm_bf16<<<dim3(2, 128), 256, 0, stream>>>(act1, wb2, bb2, act2, BATCH, 256, 512);
    gemm_bf16<<<dim3(1, 128), 256, 0, stream>>>(act2, wb3, bb3, bot, BATCH, 128, 256);

    interact_mfma<<<BATCH / 4, 256, 0, stream>>>(bot, cat, tables, xbuf);

    gemm_bf16<<<dim3(8, 128), 256, 0, stream>>>(xbuf, wt1, tb1, h1, BATCH, 1024, 480);
    gemm_bf16<<<dim3(8, 128), 256, 0, stream>>>(h1, wt2, tb2, h2, BATCH, 1024, 1024);
    gemm_bf16<<<dim3(4, 128), 256, 0, stream>>>(h2, wt3, tb3, h3, BATCH, 512, 1024);
    gemm_bf16<<<dim3(2, 128), 256, 0, stream>>>(h3, wt4, tb4, h4, BATCH, 256, 512);

    top_final<<<BATCH / 4, 256, 0, stream>>>(h4, tw5, tb5, out);
}